// Round 10
// baseline (431.007 us; speedup 1.0000x reference)
//
#include <hip/hip_runtime.h>

#define E_CONST 3
#define T_CONST 100
#define C10 10.0f
#define ALPHA_C 0.05f
#define SPLIT 4
#define MAXK 8192
#define NGROUP (E_CONST * 2 * T_CONST)   // 600

__device__ inline int waveInclScan(int v, int lane) {
    #pragma unroll
    for (int off = 1; off < 64; off <<= 1) {
        int n = __shfl_up(v, off, 64);
        if (lane >= off) v += n;
    }
    return v;
}

// ---------------------------------------------------------------------------
// combo (512 thr): blocks [0, prepBlocks) = prep (64 rows/block: contiguous
// float4 loads -> LDS tile -> bit-identical sequential row scan -> coalesced
// transposed stores). Blocks [prepBlocks, prepBlocks+75) = thrfill: one WAVE
// per group, ballot-compacting (s-order, deterministic, no atomics) threshold
// values exp(10 * rowsum(event_out[i][s][0..col])) into thrVals + gCnt.
// thrfill does NOT read cumT — the row prefix sum is recomputed from
// event_out with the SAME sequential add order as prep's scan -> values are
// bit-identical to cumT[i][col][s]. Disjoint outputs -> one dispatch.
// R9 lesson: keep the sweep grid at 2400 blocks; R5 lesson: no device fences.
// ---------------------------------------------------------------------------
__global__ __launch_bounds__(512) void combo_kernel(
    const float* __restrict__ event_out, const int* __restrict__ et,
    const int* __restrict__ labs, float* __restrict__ cumT,
    float* __restrict__ thrVals, int* __restrict__ gCnt,
    int prepBlocks, int S)
{
    __shared__ float tile[64][101];        // pad 101 -> scan reads 2-way free
    const int tid = threadIdx.x;

    if ((int)blockIdx.x < prepBlocks) {
        // ---------------- prep half: 64 rows per block ----------------
        const int rowbase = (int)blockIdx.x * 64;              // in [0, E*S)
        const float4* __restrict__ src =
            reinterpret_cast<const float4*>(event_out) + (size_t)rowbase * 25;
        for (int idx = tid; idx < 64 * 25; idx += 512) {       // contiguous 25.6KB
            const float4 v = src[idx];
            const int r = idx / 25;
            const int c = idx - r * 25;
            float* d = &tile[r][c * 4];
            d[0] = v.x; d[1] = v.y; d[2] = v.z; d[3] = v.w;
        }
        __syncthreads();
        if (tid < 64) {                                        // sequential adds
            float run = 0.f;
            #pragma unroll 4
            for (int c = 0; c < T_CONST; ++c) { run += tile[tid][c]; tile[tid][c] = run; }
        }
        __syncthreads();
        const int i  = rowbase / S;
        const int s0 = rowbase - i * S;
        float* __restrict__ dst = cumT + (size_t)i * T_CONST * S + s0;
        for (int idx = tid; idx < 64 * T_CONST; idx += 512) {  // coalesced 256B/wave
            const int t = idx >> 6;
            const int r = idx & 63;
            dst[(size_t)t * S + r] = tile[r][t];
        }
        return;
    }

    // ---------------- thrfill half: one wave per group ----------------
    const int lane = tid & 63;
    const int gid = ((int)blockIdx.x - prepBlocks) * 8 + (tid >> 6);  // 0..599
    if (gid >= NGROUP) return;
    const int i = gid / 200;
    const int r = gid - i * 200;
    const int dir = r / 100;
    const int tt = r - dir * 100;

    const int colIdx = tt;
    int t1 = 0, t2 = -1;
    bool any = true;
    if (dir == 0) { t1 = tt; }
    else {
        const int cb = tt;
        if (cb >= T_CONST - 1) any = false;     // bwd cb=99 unused
        t1 = cb + 1;
        if (cb > 0) t2 = cb;
    }

    int cnt = 0;
    if (any) {
        float* __restrict__ dst = thrVals + (size_t)gid * MAXK;
        const int nfull = (colIdx + 1) >> 2;
        const int rem   = (colIdx + 1) & 3;
        for (int s0 = 0; s0 < S; s0 += 64) {
            const int s = s0 + lane;
            const int ts = et[s * E_CONST + i];
            const int ls = labs[s * E_CONST + i];
            const bool pred = ((ts == t1) & (ls == 1)) |
                              ((t2 >= 0) & (ts == t2) & (ls == 0));
            const unsigned long long mask = __ballot(pred);
            if (pred) {
                const int off = __popcll(mask & ((1ull << lane) - 1ull));
                // row prefix sum, SAME sequential order as prep's scan
                const float4* __restrict__ row4 = reinterpret_cast<const float4*>(
                    event_out + ((size_t)i * S + s) * T_CONST);
                float run = 0.f;
                for (int c = 0; c < nfull; ++c) {
                    const float4 v = row4[c];
                    run += v.x; run += v.y; run += v.z; run += v.w;
                }
                if (rem) {
                    const float4 v = row4[nfull];
                    run += v.x;
                    if (rem > 1) run += v.y;
                    if (rem > 2) run += v.z;
                }
                dst[cnt + off] = __expf(C10 * run);
            }
            cnt += (int)__popcll(mask);
        }
    }
    if (lane == 0) gCnt[gid] = cnt;
}

// ---------------------------------------------------------------------------
// grouppair v5 (R8-proven, bit-deterministic): one block per (event, t-bin,
// direction, S/4-chunk) = 2400 blocks. Membership staged via predicates +
// deterministic block-scan compact; thresholds read CONTIGUOUSLY from
// thrVals/gCnt. Sweep: proven 32-thresholds/pass, 8-strip broadcast form.
// ---------------------------------------------------------------------------
__global__ __launch_bounds__(256) void grouppair_kernel(
    const float* __restrict__ cumT, const float* __restrict__ thrVals,
    const int* __restrict__ gCnt, const int* __restrict__ et,
    const int* __restrict__ labs, float* __restrict__ partials, int S)
{
    __shared__ __align__(16) float elds[2048];
    __shared__ float wsum[4];
    __shared__ int wcnt[4];
    __shared__ int nTot;
    const int tid = threadIdx.x;
    const int lane = tid & 63, wid = tid >> 6;

    int x = (int)blockIdx.x;
    const int sp = x & (SPLIT - 1); x >>= 2;
    const int dir = x & 1;          x >>= 1;
    const int tt = x % T_CONST;
    const int i  = x / T_CONST;

    int colIdx = 0, tref = 0, tgid = 0;
    bool active = true;                     // block-uniform
    if (dir == 0) { colIdx = tt; tref = tt; tgid = i * 200 + tt; }
    else {
        const int cb = (T_CONST - 2) - tt;  // heavy (large cb) first
        if (cb < 0) active = false;
        else { colIdx = cb; tref = cb; tgid = i * 200 + 100 + cb; }
    }
    const int K = active ? gCnt[tgid] : 0;
    if (K <= 0) active = false;

    float blocktot = 0.f;
    if (active) {                           // block-uniform branch
        const float* __restrict__ col = cumT + ((size_t)i * T_CONST + colIdx) * S;
        const float sgn = (dir == 0) ? C10 : -C10;
        const int chunk = S / SPLIT;        // 2048 (launcher guarantees)
        const int cbeg = sp * chunk;

        // ---- membership staging (deterministic compact) ----
        float ev[8];
        int mask = 0, m = 0;
        #pragma unroll
        for (int j = 0; j < 8; ++j) {
            const int s = cbeg + tid + j * 256;
            const int ts = et[s * E_CONST + i];
            const int ls = labs[s * E_CONST + i];
            const bool mem = (dir == 0)
                ? ((ts > tref) | ((ts == tref) & (ls == 0)))
                : ((ts <= tref) & (ls == 1));
            ev[j] = __expf(sgn * col[s]);
            if (mem) { mask |= (1 << j); ++m; }
        }
        const int incl = waveInclScan(m, lane);
        if (lane == 63) wcnt[wid] = incl;
        __syncthreads();
        int off = 0;
        for (int w = 0; w < wid; ++w) off += wcnt[w];
        int base = incl - m + off;
        #pragma unroll
        for (int j = 0; j < 8; ++j)
            if (mask & (1 << j)) elds[base++] = ev[j];
        if (tid == 255) {                   // base == total member count
            nTot = base;
            const int np = (base + 3) & ~3;
            for (int p = base; p < np; ++p) elds[p] = 0.f;   // float4 pad
        }
        __syncthreads();

        const int n = nTot;
        if (n > 0) {                        // block-uniform
            const int qn4 = ((n + 3) & ~3) >> 2;
            const int kq = tid & 31;        // threshold lane
            const int ep = tid >> 5;        // element strip 0..7
            const float4* __restrict__ e4 = reinterpret_cast<const float4*>(elds);
            const float* __restrict__ tv = thrVals + (size_t)tgid * MAXK;
            const int nkc = (K + 31) >> 5;

            for (int kc = 0; kc < nkc; ++kc) {
                const int j = (kc << 5) + kq;
                float thr = 1e30f, factor = 0.f;
                if (j < K) {
                    const float tval = tv[j];               // contiguous, L2-hot
                    if (dir == 0) { thr = tval;        factor = 1.0f / tval; }
                    else          { thr = 1.0f / tval; factor = tval; }
                }
                float acc = 0.f;
                for (int q = ep; q < qn4; q += 8) {         // LDS broadcast reads
                    const float4 v = e4[q];
                    acc += (v.x > thr) ? v.x : 0.f;
                    acc += (v.y > thr) ? v.y : 0.f;
                    acc += (v.z > thr) ? v.z : 0.f;
                    acc += (v.w > thr) ? v.w : 0.f;
                }
                blocktot += acc * factor;
            }
        }
    }

    for (int off = 32; off > 0; off >>= 1) blocktot += __shfl_down(blocktot, off, 64);
    if (lane == 0) wsum[wid] = blocktot;
    __syncthreads();
    if (tid == 0) partials[blockIdx.x] = wsum[0] + wsum[1] + wsum[2] + wsum[3];
}

// ---------------------------------------------------------------------------
// reduce: fixed-order, deterministic. float4 loads, 4 accumulators.
// ---------------------------------------------------------------------------
__global__ __launch_bounds__(1024) void reduce_kernel(
    const float* __restrict__ partials, int n, float* __restrict__ out)
{
    const int tid = threadIdx.x;
    float s0 = 0.f, s1 = 0.f, s2 = 0.f, s3 = 0.f;
    const int n4 = n & ~3;
    for (int idx = tid * 4; idx < n4; idx += 4096) {
        const float4 v = *reinterpret_cast<const float4*>(partials + idx);
        s0 += v.x; s1 += v.y; s2 += v.z; s3 += v.w;
    }
    for (int idx = n4 + tid; idx < n; idx += 1024) s0 += partials[idx];
    float sum = (s0 + s1) + (s2 + s3);
    for (int off = 32; off > 0; off >>= 1) sum += __shfl_down(sum, off, 64);
    __shared__ float wsum[16];
    const int lane = tid & 63, wd = tid >> 6;
    if (lane == 0) wsum[wd] = sum;
    __syncthreads();
    if (tid == 0) {
        float t = 0.f;
        for (int w = 0; w < 16; ++w) t += wsum[w];
        out[0] = ALPHA_C * t;
    }
}

// ---------------------------------------------------------------------------
// fallback (R1-proven structure, deterministic): used only if ws_size is too
// small or shape assumptions don't hold.
// ---------------------------------------------------------------------------
__global__ __launch_bounds__(64) void prep_fb_kernel(
    const float* __restrict__ event_out, const int* __restrict__ et,
    const int* __restrict__ labs, float* __restrict__ cumT,
    int* __restrict__ tlA, int S)
{
    const int gid = blockIdx.x * 64 + threadIdx.x;
    const int i = gid / S;
    const int s = gid - i * S;
    const float4* __restrict__ row =
        reinterpret_cast<const float4*>(event_out + (size_t)gid * T_CONST);
    float* __restrict__ base = cumT + (size_t)i * T_CONST * S + s;
    float run = 0.f;
    #pragma unroll
    for (int c = 0; c < T_CONST / 4; ++c) {
        const float4 v = row[c];
        const float c0 = run + v.x;
        const float c1 = c0 + v.y;
        const float c2 = c1 + v.z;
        const float c3 = c2 + v.w;
        base[(size_t)(4 * c + 0) * S] = c0;
        base[(size_t)(4 * c + 1) * S] = c1;
        base[(size_t)(4 * c + 2) * S] = c2;
        base[(size_t)(4 * c + 3) * S] = c3;
        run = c3;
    }
    const int t   = et[s * E_CONST + i];
    const int lab = labs[s * E_CONST + i];
    tlA[i * S + s] = (t & 0xffff) | (lab << 16);
}

__global__ __launch_bounds__(256) void pair_fb_kernel(
    const float* __restrict__ cumT, const int* __restrict__ tlA,
    float* __restrict__ partials, int S)
{
    const int bx = blockIdx.x;
    const int i = bx / S;
    const int k = bx - i * S;
    const int base = i * S;
    const int tlk = tlA[base + k];
    const int t_k = tlk & 0xffff;
    const int lab_k = tlk >> 16;
    const bool doF = (lab_k == 1);
    const bool doB = (t_k > 0);
    float sum = 0.f;
    if (doF || doB) {
        const int cb = lab_k ? (t_k > 0 ? t_k - 1 : 0) : t_k;
        const float* __restrict__ colF = cumT + ((size_t)i * T_CONST + t_k) * S;
        const float* __restrict__ colB = cumT + ((size_t)i * T_CONST + cb)  * S;
        const float vf_k = colF[k];
        const float vb_k = colB[k];
        const int* __restrict__ tlp = tlA + base;
        for (int s = threadIdx.x; s < S; s += 256) {
            const int tls = tlp[s];
            const int t_s = tls & 0xffff;
            const int lab_s = tls >> 16;
            if (doF) {
                const float vs = colF[s];
                const bool c = (t_s > t_k) | ((t_s == t_k) & (lab_s == 0));
                if (c & (vs > vf_k)) sum += __expf((vs - vf_k) * C10);
            }
            if (doB) {
                const float vs = colB[s];
                const bool c = (t_s <= cb) & (lab_s == 1);
                if (c & (vb_k > vs)) sum += __expf((vb_k - vs) * C10);
            }
        }
    }
    for (int off = 32; off > 0; off >>= 1) sum += __shfl_down(sum, off, 64);
    __shared__ float wsum[4];
    const int lane = threadIdx.x & 63, wd = threadIdx.x >> 6;
    if (lane == 0) wsum[wd] = sum;
    __syncthreads();
    if (threadIdx.x == 0) partials[bx] = wsum[0] + wsum[1] + wsum[2] + wsum[3];
}

extern "C" void kernel_launch(void* const* d_in, const int* in_sizes, int n_in,
                              void* d_out, int out_size, void* d_ws, size_t ws_size,
                              hipStream_t stream)
{
    const float* event_out = (const float*)d_in[0];  // (E,S,T) fp32
    const int*   et        = (const int*)d_in[1];    // (S,E) int32
    const int*   labsp     = (const int*)d_in[2];    // (S,E) int32
    const int S = in_sizes[1] / E_CONST;             // 8192

    const size_t colElems = (size_t)E_CONST * T_CONST * S;
    const size_t esElems  = (size_t)E_CONST * S;
    const int    gpBlocks = E_CONST * T_CONST * 2 * SPLIT;   // 2400

    char* p = (char*)d_ws;
    float* cumT     = (float*)p; p += colElems * 4;
    float* thrVals  = (float*)p; p += (size_t)NGROUP * MAXK * 4;   // 19.7 MB
    int*   gCnt     = (int*)p;   p += (size_t)NGROUP * 4;
    float* partials = (float*)p; p += (size_t)gpBlocks * 4;
    const size_t needed = (size_t)(p - (char*)d_ws);
    const size_t fallback_needed = colElems * 4 + esElems * 4 * 2;

    const int prepBlocks = (E_CONST * S) / 64;       // 384 (S % 64 == 0)
    const int thrBlocks  = NGROUP / 8;               // 75 (8 waves/block)

    // main path requires: rows divisible by 64, chunk == 2048 (= 8*256),
    // S divisible by 256, and S <= MAXK (thrfill fixed stride)
    if (ws_size >= needed && (E_CONST * S) % 64 == 0 &&
        (S / SPLIT) == 2048 && (S % 256) == 0 && S <= MAXK) {
        hipLaunchKernelGGL(combo_kernel, dim3(prepBlocks + thrBlocks), dim3(512), 0, stream,
                           event_out, et, labsp, cumT, thrVals, gCnt,
                           prepBlocks, S);
        hipLaunchKernelGGL(grouppair_kernel, dim3(gpBlocks), dim3(256), 0, stream,
                           cumT, thrVals, gCnt, et, labsp, partials, S);
        hipLaunchKernelGGL(reduce_kernel, dim3(1), dim3(1024), 0, stream,
                           partials, gpBlocks, (float*)d_out);
    } else if (ws_size >= fallback_needed) {
        const int nB = E_CONST * S;
        float* cumT2     = (float*)d_ws;
        int*   tlA2      = (int*)(cumT2 + colElems);
        float* partials2 = (float*)(tlA2 + esElems);
        hipLaunchKernelGGL(prep_fb_kernel, dim3(E_CONST * S / 64), dim3(64), 0, stream,
                           event_out, et, labsp, cumT2, tlA2, S);
        hipLaunchKernelGGL(pair_fb_kernel, dim3(nB), dim3(256), 0, stream,
                           cumT2, tlA2, partials2, S);
        hipLaunchKernelGGL(reduce_kernel, dim3(1), dim3(1024), 0, stream,
                           partials2, nB, (float*)d_out);
    }
}

// Round 11
// 116.039 us; speedup vs baseline: 3.7143x; 3.7143x over previous
//
#include <hip/hip_runtime.h>

#define E_CONST 3
#define T_CONST 100
#define C10 10.0f
#define ALPHA_C 0.05f
#define SPLIT 4
#define MAXK 8192
#define NGROUP (E_CONST * 2 * T_CONST)   // 600

__device__ inline int waveInclScan(int v, int lane) {
    #pragma unroll
    for (int off = 1; off < 64; off <<= 1) {
        int n = __shfl_up(v, off, 64);
        if (lane >= off) v += n;
    }
    return v;
}

// ---------------------------------------------------------------------------
// prep (512 thr, 64 rows/block): contiguous float4 loads -> LDS tile ->
// bit-identical sequential row scan -> coalesced transposed stores.
// Fully deterministic. (R9/R10 lesson: do NOT fuse other stages into this
// dispatch — tail blocks lose occupancy and serialize.)
// ---------------------------------------------------------------------------
__global__ __launch_bounds__(512) void prep_kernel(
    const float* __restrict__ event_out, float* __restrict__ cumT, int S)
{
    __shared__ float tile[64][101];        // pad 101 -> scan reads 2-way free
    const int tid = threadIdx.x;
    const int rowbase = (int)blockIdx.x * 64;              // in [0, E*S)
    const float4* __restrict__ src =
        reinterpret_cast<const float4*>(event_out) + (size_t)rowbase * 25;
    for (int idx = tid; idx < 64 * 25; idx += 512) {       // contiguous 25.6KB
        const float4 v = src[idx];
        const int r = idx / 25;
        const int c = idx - r * 25;
        float* d = &tile[r][c * 4];
        d[0] = v.x; d[1] = v.y; d[2] = v.z; d[3] = v.w;
    }
    __syncthreads();
    if (tid < 64) {                                        // same add order as before
        float run = 0.f;
        #pragma unroll 4
        for (int c = 0; c < T_CONST; ++c) { run += tile[tid][c]; tile[tid][c] = run; }
    }
    __syncthreads();
    const int i  = rowbase / S;
    const int s0 = rowbase - i * S;
    float* __restrict__ dst = cumT + (size_t)i * T_CONST * S + s0;
    for (int idx = tid; idx < 64 * T_CONST; idx += 512) {  // coalesced 256B/wave
        const int t = idx >> 6;
        const int r = idx & 63;
        dst[(size_t)t * S + r] = tile[r][t];
    }
}

// ---------------------------------------------------------------------------
// thrfill v2: one BLOCK (256 thr) per group = 600 blocks (2.3/CU, full
// machine — fixes R8's wave-serial 32-iteration shape). Scans S in 8
// iterations of 1024 (4 consecutive s per thread -> coalesced float4 col
// reads); compacts threshold values exp(10*col[s]) into thrVals in s-order
// via the deterministic block-scan pattern proven in grouppair. No atomics.
// Groups: gid = i*200 + t        (fwd: pred t_s==t & lab==1, col t)
//         gid = i*200 + 100 + cb (bwd: pred (t_s==cb+1 & lab==1) |
//                                  (cb>0 & t_s==cb & lab==0), col cb)
// ---------------------------------------------------------------------------
__global__ __launch_bounds__(256) void thrfill_kernel(
    const float* __restrict__ cumT, const int* __restrict__ et,
    const int* __restrict__ labs, float* __restrict__ thrVals,
    int* __restrict__ gCnt, int S)
{
    __shared__ int wcnt[4];
    const int tid = threadIdx.x;
    const int lane = tid & 63, wid = tid >> 6;
    const int gid = (int)blockIdx.x;            // 0..599
    const int i = gid / 200;
    const int r = gid - i * 200;
    const int dir = r / 100;
    const int tt = r - dir * 100;

    const int colIdx = tt;
    int t1 = 0, t2 = -1;
    bool any = true;                            // block-uniform
    if (dir == 0) { t1 = tt; }
    else {
        const int cb = tt;
        if (cb >= T_CONST - 1) any = false;     // bwd cb=99 unused
        t1 = cb + 1;
        if (cb > 0) t2 = cb;
    }

    int cnt = 0;
    if (any) {
        const float* __restrict__ col = cumT + ((size_t)i * T_CONST + colIdx) * S;
        float* __restrict__ dst = thrVals + (size_t)gid * MAXK;
        for (int s0 = 0; s0 < S; s0 += 1024) {
            const int sb = s0 + tid * 4;        // 4 consecutive s per thread
            const float4 cv = *reinterpret_cast<const float4*>(col + sb);
            float tv[4]; int mask = 0, m = 0;
            #pragma unroll
            for (int j = 0; j < 4; ++j) {
                const int s = sb + j;
                const int ts = et[s * E_CONST + i];
                const int ls = labs[s * E_CONST + i];
                const float c = (j == 0) ? cv.x : (j == 1) ? cv.y
                              : (j == 2) ? cv.z : cv.w;
                tv[j] = __expf(C10 * c);        // stored only if pred
                const bool p = ((ts == t1) & (ls == 1)) |
                               ((t2 >= 0) & (ts == t2) & (ls == 0));
                if (p) { mask |= (1 << j); ++m; }
            }
            const int incl = waveInclScan(m, lane);
            if (lane == 63) wcnt[wid] = incl;
            __syncthreads();
            int base = cnt + incl - m;
            for (int w = 0; w < wid; ++w) base += wcnt[w];
            #pragma unroll
            for (int j = 0; j < 4; ++j)
                if (mask & (1 << j)) dst[base++] = tv[j];
            cnt += wcnt[0] + wcnt[1] + wcnt[2] + wcnt[3];
            __syncthreads();                    // wcnt rewrite next iter
        }
    }
    if (tid == 0) gCnt[gid] = cnt;
}

// ---------------------------------------------------------------------------
// grouppair v5 (R8-proven, bit-deterministic): one block per (event, t-bin,
// direction, S/4-chunk) = 2400 blocks. Membership staged via predicates +
// deterministic block-scan compact; thresholds read CONTIGUOUSLY from
// thrVals/gCnt. Sweep: proven 32-thresholds/pass, 8-strip broadcast form.
// R5 lesson: no device fences; separate tiny reduce kernel.
// ---------------------------------------------------------------------------
__global__ __launch_bounds__(256) void grouppair_kernel(
    const float* __restrict__ cumT, const float* __restrict__ thrVals,
    const int* __restrict__ gCnt, const int* __restrict__ et,
    const int* __restrict__ labs, float* __restrict__ partials, int S)
{
    __shared__ __align__(16) float elds[2048];
    __shared__ float wsum[4];
    __shared__ int wcnt[4];
    __shared__ int nTot;
    const int tid = threadIdx.x;
    const int lane = tid & 63, wid = tid >> 6;

    int x = (int)blockIdx.x;
    const int sp = x & (SPLIT - 1); x >>= 2;
    const int dir = x & 1;          x >>= 1;
    const int tt = x % T_CONST;
    const int i  = x / T_CONST;

    int colIdx = 0, tref = 0, tgid = 0;
    bool active = true;                     // block-uniform
    if (dir == 0) { colIdx = tt; tref = tt; tgid = i * 200 + tt; }
    else {
        const int cb = (T_CONST - 2) - tt;  // heavy (large cb) first
        if (cb < 0) active = false;
        else { colIdx = cb; tref = cb; tgid = i * 200 + 100 + cb; }
    }
    const int K = active ? gCnt[tgid] : 0;
    if (K <= 0) active = false;

    float blocktot = 0.f;
    if (active) {                           // block-uniform branch
        const float* __restrict__ col = cumT + ((size_t)i * T_CONST + colIdx) * S;
        const float sgn = (dir == 0) ? C10 : -C10;
        const int chunk = S / SPLIT;        // 2048 (launcher guarantees)
        const int cbeg = sp * chunk;

        // ---- membership staging (deterministic compact) ----
        float ev[8];
        int mask = 0, m = 0;
        #pragma unroll
        for (int j = 0; j < 8; ++j) {
            const int s = cbeg + tid + j * 256;
            const int ts = et[s * E_CONST + i];
            const int ls = labs[s * E_CONST + i];
            const bool mem = (dir == 0)
                ? ((ts > tref) | ((ts == tref) & (ls == 0)))
                : ((ts <= tref) & (ls == 1));
            ev[j] = __expf(sgn * col[s]);
            if (mem) { mask |= (1 << j); ++m; }
        }
        const int incl = waveInclScan(m, lane);
        if (lane == 63) wcnt[wid] = incl;
        __syncthreads();
        int off = 0;
        for (int w = 0; w < wid; ++w) off += wcnt[w];
        int base = incl - m + off;
        #pragma unroll
        for (int j = 0; j < 8; ++j)
            if (mask & (1 << j)) elds[base++] = ev[j];
        if (tid == 255) {                   // base == total member count
            nTot = base;
            const int np = (base + 3) & ~3;
            for (int p = base; p < np; ++p) elds[p] = 0.f;   // float4 pad
        }
        __syncthreads();

        const int n = nTot;
        if (n > 0) {                        // block-uniform
            const int qn4 = ((n + 3) & ~3) >> 2;
            const int kq = tid & 31;        // threshold lane
            const int ep = tid >> 5;        // element strip 0..7
            const float4* __restrict__ e4 = reinterpret_cast<const float4*>(elds);
            const float* __restrict__ tv = thrVals + (size_t)tgid * MAXK;
            const int nkc = (K + 31) >> 5;

            for (int kc = 0; kc < nkc; ++kc) {
                const int j = (kc << 5) + kq;
                float thr = 1e30f, factor = 0.f;
                if (j < K) {
                    const float tval = tv[j];               // contiguous, L2-hot
                    if (dir == 0) { thr = tval;        factor = 1.0f / tval; }
                    else          { thr = 1.0f / tval; factor = tval; }
                }
                float acc = 0.f;
                for (int q = ep; q < qn4; q += 8) {         // LDS broadcast reads
                    const float4 v = e4[q];
                    acc += (v.x > thr) ? v.x : 0.f;
                    acc += (v.y > thr) ? v.y : 0.f;
                    acc += (v.z > thr) ? v.z : 0.f;
                    acc += (v.w > thr) ? v.w : 0.f;
                }
                blocktot += acc * factor;
            }
        }
    }

    for (int off = 32; off > 0; off >>= 1) blocktot += __shfl_down(blocktot, off, 64);
    if (lane == 0) wsum[wid] = blocktot;
    __syncthreads();
    if (tid == 0) partials[blockIdx.x] = wsum[0] + wsum[1] + wsum[2] + wsum[3];
}

// ---------------------------------------------------------------------------
// reduce: fixed-order, deterministic. float4 loads, 4 accumulators.
// ---------------------------------------------------------------------------
__global__ __launch_bounds__(1024) void reduce_kernel(
    const float* __restrict__ partials, int n, float* __restrict__ out)
{
    const int tid = threadIdx.x;
    float s0 = 0.f, s1 = 0.f, s2 = 0.f, s3 = 0.f;
    const int n4 = n & ~3;
    for (int idx = tid * 4; idx < n4; idx += 4096) {
        const float4 v = *reinterpret_cast<const float4*>(partials + idx);
        s0 += v.x; s1 += v.y; s2 += v.z; s3 += v.w;
    }
    for (int idx = n4 + tid; idx < n; idx += 1024) s0 += partials[idx];
    float sum = (s0 + s1) + (s2 + s3);
    for (int off = 32; off > 0; off >>= 1) sum += __shfl_down(sum, off, 64);
    __shared__ float wsum[16];
    const int lane = tid & 63, wd = tid >> 6;
    if (lane == 0) wsum[wd] = sum;
    __syncthreads();
    if (tid == 0) {
        float t = 0.f;
        for (int w = 0; w < 16; ++w) t += wsum[w];
        out[0] = ALPHA_C * t;
    }
}

// ---------------------------------------------------------------------------
// fallback (R1-proven structure, deterministic): used only if ws_size is too
// small or shape assumptions don't hold.
// ---------------------------------------------------------------------------
__global__ __launch_bounds__(64) void prep_fb_kernel(
    const float* __restrict__ event_out, const int* __restrict__ et,
    const int* __restrict__ labs, float* __restrict__ cumT,
    int* __restrict__ tlA, int S)
{
    const int gid = blockIdx.x * 64 + threadIdx.x;
    const int i = gid / S;
    const int s = gid - i * S;
    const float4* __restrict__ row =
        reinterpret_cast<const float4*>(event_out + (size_t)gid * T_CONST);
    float* __restrict__ base = cumT + (size_t)i * T_CONST * S + s;
    float run = 0.f;
    #pragma unroll
    for (int c = 0; c < T_CONST / 4; ++c) {
        const float4 v = row[c];
        const float c0 = run + v.x;
        const float c1 = c0 + v.y;
        const float c2 = c1 + v.z;
        const float c3 = c2 + v.w;
        base[(size_t)(4 * c + 0) * S] = c0;
        base[(size_t)(4 * c + 1) * S] = c1;
        base[(size_t)(4 * c + 2) * S] = c2;
        base[(size_t)(4 * c + 3) * S] = c3;
        run = c3;
    }
    const int t   = et[s * E_CONST + i];
    const int lab = labs[s * E_CONST + i];
    tlA[i * S + s] = (t & 0xffff) | (lab << 16);
}

__global__ __launch_bounds__(256) void pair_fb_kernel(
    const float* __restrict__ cumT, const int* __restrict__ tlA,
    float* __restrict__ partials, int S)
{
    const int bx = blockIdx.x;
    const int i = bx / S;
    const int k = bx - i * S;
    const int base = i * S;
    const int tlk = tlA[base + k];
    const int t_k = tlk & 0xffff;
    const int lab_k = tlk >> 16;
    const bool doF = (lab_k == 1);
    const bool doB = (t_k > 0);
    float sum = 0.f;
    if (doF || doB) {
        const int cb = lab_k ? (t_k > 0 ? t_k - 1 : 0) : t_k;
        const float* __restrict__ colF = cumT + ((size_t)i * T_CONST + t_k) * S;
        const float* __restrict__ colB = cumT + ((size_t)i * T_CONST + cb)  * S;
        const float vf_k = colF[k];
        const float vb_k = colB[k];
        const int* __restrict__ tlp = tlA + base;
        for (int s = threadIdx.x; s < S; s += 256) {
            const int tls = tlp[s];
            const int t_s = tls & 0xffff;
            const int lab_s = tls >> 16;
            if (doF) {
                const float vs = colF[s];
                const bool c = (t_s > t_k) | ((t_s == t_k) & (lab_s == 0));
                if (c & (vs > vf_k)) sum += __expf((vs - vf_k) * C10);
            }
            if (doB) {
                const float vs = colB[s];
                const bool c = (t_s <= cb) & (lab_s == 1);
                if (c & (vb_k > vs)) sum += __expf((vb_k - vs) * C10);
            }
        }
    }
    for (int off = 32; off > 0; off >>= 1) sum += __shfl_down(sum, off, 64);
    __shared__ float wsum[4];
    const int lane = threadIdx.x & 63, wd = threadIdx.x >> 6;
    if (lane == 0) wsum[wd] = sum;
    __syncthreads();
    if (threadIdx.x == 0) partials[bx] = wsum[0] + wsum[1] + wsum[2] + wsum[3];
}

extern "C" void kernel_launch(void* const* d_in, const int* in_sizes, int n_in,
                              void* d_out, int out_size, void* d_ws, size_t ws_size,
                              hipStream_t stream)
{
    const float* event_out = (const float*)d_in[0];  // (E,S,T) fp32
    const int*   et        = (const int*)d_in[1];    // (S,E) int32
    const int*   labsp     = (const int*)d_in[2];    // (S,E) int32
    const int S = in_sizes[1] / E_CONST;             // 8192

    const size_t colElems = (size_t)E_CONST * T_CONST * S;
    const size_t esElems  = (size_t)E_CONST * S;
    const int    gpBlocks = E_CONST * T_CONST * 2 * SPLIT;   // 2400

    char* p = (char*)d_ws;
    float* cumT     = (float*)p; p += colElems * 4;
    float* thrVals  = (float*)p; p += (size_t)NGROUP * MAXK * 4;   // 19.7 MB
    int*   gCnt     = (int*)p;   p += (size_t)NGROUP * 4;
    float* partials = (float*)p; p += (size_t)gpBlocks * 4;
    const size_t needed = (size_t)(p - (char*)d_ws);
    const size_t fallback_needed = colElems * 4 + esElems * 4 * 2;

    const int prepBlocks = (E_CONST * S) / 64;       // 384 (S % 64 == 0)

    // main path requires: rows divisible by 64, chunk == 2048 (= 8*256),
    // S divisible by 1024 (thrfill loop), and S <= MAXK (thrVals stride)
    if (ws_size >= needed && (E_CONST * S) % 64 == 0 &&
        (S / SPLIT) == 2048 && (S % 1024) == 0 && S <= MAXK) {
        hipLaunchKernelGGL(prep_kernel, dim3(prepBlocks), dim3(512), 0, stream,
                           event_out, cumT, S);
        hipLaunchKernelGGL(thrfill_kernel, dim3(NGROUP), dim3(256), 0, stream,
                           cumT, et, labsp, thrVals, gCnt, S);
        hipLaunchKernelGGL(grouppair_kernel, dim3(gpBlocks), dim3(256), 0, stream,
                           cumT, thrVals, gCnt, et, labsp, partials, S);
        hipLaunchKernelGGL(reduce_kernel, dim3(1), dim3(1024), 0, stream,
                           partials, gpBlocks, (float*)d_out);
    } else if (ws_size >= fallback_needed) {
        const int nB = E_CONST * S;
        float* cumT2     = (float*)d_ws;
        int*   tlA2      = (int*)(cumT2 + colElems);
        float* partials2 = (float*)(tlA2 + esElems);
        hipLaunchKernelGGL(prep_fb_kernel, dim3(E_CONST * S / 64), dim3(64), 0, stream,
                           event_out, et, labsp, cumT2, tlA2, S);
        hipLaunchKernelGGL(pair_fb_kernel, dim3(nB), dim3(256), 0, stream,
                           cumT2, tlA2, partials2, S);
        hipLaunchKernelGGL(reduce_kernel, dim3(1), dim3(1024), 0, stream,
                           partials2, nB, (float*)d_out);
    }
}